// Round 4
// baseline (387.928 us; speedup 1.0000x reference)
//
#include <hip/hip_runtime.h>
#include <hip/hip_bf16.h>

typedef __attribute__((ext_vector_type(4))) float f4v;
typedef __attribute__((ext_vector_type(8))) short bf8v;

// ---- problem constants ----
#define NPOS 32768            // 32*32*32
#define CCH  192
#define HID  768

// ---- workspace layout (bytes) ----
#define WS_Y    ((size_t)0)           // 2*512*192*64*2 = 25,165,824  conv out bf16, cell layout
#define WS_B1F  ((size_t)25165824)    // 294,912  w1 bf16 B-frag swizzled
#define WS_B2F  ((size_t)25460736)    // 294,912  w2 bf16 B-frag swizzled
// total: 25,755,648 bytes

__device__ inline unsigned short f2bf(float f){
  unsigned int u = __float_as_uint(f);
  u += 0x7FFFu + ((u >> 16) & 1u);      // RNE
  return (unsigned short)(u >> 16);
}
__device__ inline float bf2f(unsigned short s){
  return __uint_as_float(((unsigned int)s) << 16);
}
__device__ inline float gelu_f(float x){
  float u = 0.7978845608028654f * x * fmaf(0.044715f, x*x, 1.0f);
  float e = __expf(2.0f*u);
  float th = __fdividef(e - 1.0f, e + 1.0f);
  return 0.5f*x*(1.0f + th);
}

// ---------------------------------------------------------------------------
// Kernel 1: depthwise 7x7x7 conv + bias. Block = (b, c, 16x16 xy quadrant,
// 16-z half). Whole input column (22 slices x 22 rows x 24 floats, zero-padded
// halos) staged to LDS once; ONE barrier; then pure FMA with uniform weights.
// Thread = 4dx x 4dy x 1z. Output: bf16 in cell-blocked layout
// yc[((b*512+cell)*192+c)*64 + tok], tok = (z&3)*16+(y&3)*4+(x&3).
// rr loop is software-pipelined: next row's 3 f4v preloaded during FMAs.
// ---------------------------------------------------------------------------
__global__ __launch_bounds__(256) void conv_dw_kernel(
    const float* __restrict__ x, const float* __restrict__ dw_w,
    const float* __restrict__ dw_b, unsigned short* __restrict__ yc)
{
  __shared__ float ring[22*528];       // 46,464 B

  int bid = blockIdx.x;                // 3072 = 192c * 16(r)
  int c = bid % 192;
  int r = bid / 192;                   // 0..15
  int xq = r & 1, yq = (r >> 1) & 1, zh = (r >> 2) & 1, b = r >> 3;
  int tx0 = xq*16, ty0 = yq*16, zb = zh*16;

  int tid = threadIdx.x;
  const float* xsrc = x + ((size_t)(b*CCH + c))*NPOS;

  // ---- stage column: 22 slices x 22 rows x 6 aligned f4 chunks = 2904
  for (int idx = tid; idx < 2904; idx += 256) {
    int sl = idx / 132;
    int rem = idx - sl*132;
    int rr = rem / 6, ci = rem - rr*6;
    int zi = zb - 3 + sl, gy = ty0 - 3 + rr, gx = tx0 - 4 + 4*ci;
    f4v v = {0.f, 0.f, 0.f, 0.f};
    if ((unsigned)zi < 32u && (unsigned)gy < 32u && (unsigned)gx <= 28u)
      v = *(const f4v*)(xsrc + (size_t)zi*1024 + gy*32 + gx);
    *(f4v*)(ring + sl*528 + rr*24 + ci*4) = v;
  }
  __syncthreads();

  int p = tid & 15, zl = tid >> 4;     // 16 patches, 16 z-planes
  int px = p & 3, py = p >> 2;
  int y0 = py*4, px4 = px*4;
  const float* base = ring + zl*528 + y0*24 + px4;
  const float* wq = dw_w + c*343;      // wave-uniform

  float acc[16];
  #pragma unroll
  for (int i = 0; i < 16; ++i) acc[i] = 0.f;

  #pragma unroll 1                     // keep body in I-cache
  for (int s = 0; s < 7; ++s) {
    float wl[49];
    #pragma unroll
    for (int i = 0; i < 49; ++i) wl[i] = wq[s*49 + i];
    const float* sb = base + s*528;
    f4v n0 = *(const f4v*)(sb);
    f4v n1 = *(const f4v*)(sb + 4);
    f4v n2 = *(const f4v*)(sb + 8);
    #pragma unroll
    for (int rr = 0; rr < 10; ++rr) {
      f4v r0 = n0, r1 = n1, r2 = n2;
      if (rr < 9) {                    // preload next row during FMAs
        n0 = *(const f4v*)(sb + (rr+1)*24);
        n1 = *(const f4v*)(sb + (rr+1)*24 + 4);
        n2 = *(const f4v*)(sb + (rr+1)*24 + 8);
      }
      float row[12];
      row[0]=r0[0]; row[1]=r0[1]; row[2]=r0[2]; row[3]=r0[3];
      row[4]=r1[0]; row[5]=r1[1]; row[6]=r1[2]; row[7]=r1[3];
      row[8]=r2[0]; row[9]=r2[1]; row[10]=r2[2]; row[11]=r2[3];
      #pragma unroll
      for (int dy = 0; dy < 4; ++dy) {
        int ky = rr - dy;
        if (ky < 0 || ky > 6) continue;          // compile-time pruned
        #pragma unroll
        for (int kx = 0; kx < 7; ++kx) {
          float w = wl[ky*7 + kx];
          #pragma unroll
          for (int dx = 0; dx < 4; ++dx)
            acc[dy*4 + dx] = fmaf(w, row[dx + kx + 1], acc[dy*4 + dx]);
        }
      }
    }
  }

  // ---- store bf16 to cell-blocked layout
  float bias = dw_b[c];
  int z = zb + zl;
  int cz = z >> 2, cx = (tx0 >> 2) + px, cy = (ty0 >> 2) + py;
  int cell = cz*64 + cy*8 + cx;
  unsigned short* ybase = yc + (((size_t)(b*512 + cell))*192 + c)*64;
  int tokz = (z & 3)*16;
  #pragma unroll
  for (int dy = 0; dy < 4; ++dy) {
    ushort4 o;
    o.x = f2bf(acc[dy*4+0] + bias);
    o.y = f2bf(acc[dy*4+1] + bias);
    o.z = f2bf(acc[dy*4+2] + bias);
    o.w = f2bf(acc[dy*4+3] + bias);
    *(ushort4*)(ybase + tokz + dy*4) = o;
  }
}

// ---------------------------------------------------------------------------
// Kernel 2: weight prep. w1/w2 -> bf16 MFMA-B-fragment order.
// B-frag (16x16x32): element (k,n) -> lane=((k%32)/8)*16+(n%16), byte j=k%8.
// ---------------------------------------------------------------------------
__global__ __launch_bounds__(256) void prep_w_kernel(
    const float* __restrict__ w1, const float* __restrict__ w2,
    unsigned short* __restrict__ b1f, unsigned short* __restrict__ b2f)
{
  int gid = blockIdx.x*256 + threadIdx.x;
  if (gid < 18432) {
    int fi = gid;                         // w1 (C=192 x HID=768)
    int lane = fi & 63, fr = fi >> 6;
    int nt = fr / 6, ks = fr - nt*6;
    int n  = nt*16 + (lane & 15);
    int kb = ks*32 + (lane >> 4)*8;
    #pragma unroll
    for (int j = 0; j < 8; ++j) b1f[fi*8 + j] = f2bf(w1[(kb+j)*HID + n]);
  } else if (gid < 36864) {
    int fi = gid - 18432;                 // w2 (HID=768 x C=192)
    int lane = fi & 63, fr = fi >> 6;
    int nt = fr / 24, ks = fr - nt*24;
    int n  = nt*16 + (lane & 15);
    int kb = ks*32 + (lane >> 4)*8;
    #pragma unroll
    for (int j = 0; j < 8; ++j) b2f[fi*8 + j] = f2bf(w2[(kb+j)*CCH + n]);
  }
}

// ---------------------------------------------------------------------------
// Kernel 3: fused LN + MLP per active cell. LN stats read yc directly
// (coalesced, lanes=tokens); A-fragments built from the same L1-warm lines.
// ch loop NOT unrolled (I-cache); hbuf double-buffered (1 barrier/ch).
// LDS ~36.8 KB -> 4 blocks/CU. Inactive cells: zero-fill out.
// ---------------------------------------------------------------------------
__global__ __launch_bounds__(256) void mlp_kernel(
    const unsigned short* __restrict__ yc, const unsigned short* __restrict__ b1f,
    const unsigned short* __restrict__ b2f, const float* __restrict__ b1,
    const float* __restrict__ b2, const float* __restrict__ gamma,
    const float* __restrict__ ln_w, const float* __restrict__ ln_b,
    const int* __restrict__ mask, float* __restrict__ out)
{
  int bid = blockIdx.x;
  int b = bid >> 9, cell = bid & 511;
  int cz = cell >> 6, cy = (cell >> 3) & 7, cx = cell & 7;
  int z0 = cz*4, y0 = cy*4, x0 = cx*4;
  int tid = threadIdx.x, wave = tid >> 6, lane = tid & 63;
  int lq = lane >> 4, ln15 = lane & 15;

  if (mask[bid] == 0) {
    f4v z4 = {0.f, 0.f, 0.f, 0.f};
    #pragma unroll
    for (int pp = 0; pp < 12; ++pp) {
      int i4 = tid + 256*pp;              // 0..3071
      int c = i4 >> 4, rem = i4 & 15;
      int dz = rem >> 2, dy = rem & 3;
      *(f4v*)(out + ((size_t)(b*CCH + c))*NPOS
                  + (size_t)(z0+dz)*1024 + (y0+dy)*32 + x0) = z4;
    }
    return;
  }

  __shared__ unsigned short hbuf[2][8192];  // 32 KB, A2-frag order, dbuf
  __shared__ float sred[2][4][64];
  __shared__ float murs[2][64];
  __shared__ float lnwb[2][192];

  const unsigned short* ysrc = yc + (size_t)bid*12288;

  // ---- LN stats from global, coalesced (lanes = tokens)
  {
    int tok = tid & 63, part = tid >> 6;
    float S = 0.f, Q = 0.f;
    #pragma unroll
    for (int j = 0; j < 48; ++j) {
      float v = bf2f(ysrc[(part*48 + j)*64 + tok]);
      S += v; Q = fmaf(v, v, Q);
    }
    sred[0][part][tok] = S; sred[1][part][tok] = Q;
  }
  if (tid < 192) { lnwb[0][tid] = ln_w[tid]; lnwb[1][tid] = ln_b[tid]; }
  __syncthreads();
  if (tid < 64) {
    float S = sred[0][0][tid] + sred[0][1][tid] + sred[0][2][tid] + sred[0][3][tid];
    float Q = sred[1][0][tid] + sred[1][1][tid] + sred[1][2][tid] + sred[1][3][tid];
    float m = S*(1.f/192.f);
    float var = Q*(1.f/192.f) - m*m;
    murs[0][tid] = m;
    murs[1][tid] = rsqrtf(var + 1e-6f);
  }
  __syncthreads();

  // ---- build A-fragments in registers from L1-warm global lines
  bf8v A[4][6];
  #pragma unroll
  for (int mt = 0; mt < 4; ++mt) {
    int tok = mt*16 + ln15;
    float m = murs[0][tok], rs = murs[1][tok];
    #pragma unroll
    for (int ks = 0; ks < 6; ++ks) {
      int c0 = ks*32 + lq*8;
      union { bf8v v; unsigned short u[8]; } pk;
      #pragma unroll
      for (int j = 0; j < 8; ++j) {
        int cc = c0 + j;
        float v = (bf2f(ysrc[cc*64 + tok]) - m)*rs*lnwb[0][cc] + lnwb[1][cc];
        pk.u[j] = f2bf(v);
      }
      A[mt][ks] = pk.v;
    }
  }

  f4v acc2[4][3];
  #pragma unroll
  for (int mt = 0; mt < 4; ++mt)
    #pragma unroll
    for (int nt = 0; nt < 3; ++nt)
      acc2[mt][nt] = (f4v){0.f, 0.f, 0.f, 0.f};

  #pragma unroll 1                       // keep body ~6.5 KB in I-cache
  for (int ch = 0; ch < 6; ++ch) {
    unsigned short* hb = hbuf[ch & 1];
    // ---- GEMM1 (jj-split): h[:, nt*16..+16), nt = ch*8 + wave*2 + jj
    #pragma unroll
    for (int jj = 0; jj < 2; ++jj) {
      int nt = ch*8 + wave*2 + jj;
      f4v a1[4];
      #pragma unroll
      for (int mt = 0; mt < 4; ++mt) a1[mt] = (f4v){0.f, 0.f, 0.f, 0.f};
      #pragma unroll
      for (int ks = 0; ks < 6; ++ks) {
        bf8v Bf = *(const bf8v*)(b1f + ((nt*6 + ks)*64 + lane)*8);
        #pragma unroll
        for (int mt = 0; mt < 4; ++mt)
          a1[mt] = __builtin_amdgcn_mfma_f32_16x16x32_bf16(A[mt][ks], Bf, a1[mt], 0, 0, 0);
      }
      float b1v = b1[nt*16 + ln15];
      int lane_hi = jj*2 + (ln15 >> 3);
      #pragma unroll
      for (int mt = 0; mt < 4; ++mt)
        #pragma unroll
        for (int rr = 0; rr < 4; ++rr) {
          float g = gelu_f(a1[mt][rr] + b1v);
          int elem = ((mt*4 + wave)*64 + lane_hi*16 + (lq*4 + rr))*8 + (lane & 7);
          hb[elem] = f2bf(g);
        }
    }
    __syncthreads();                     // single barrier per ch (dbuf)
    // ---- GEMM2 partial: acc2 += h_chunk @ w2[ch*128.., :]
    #pragma unroll
    for (int ks2 = 0; ks2 < 4; ++ks2) {
      bf8v A2[4];
      #pragma unroll
      for (int mt = 0; mt < 4; ++mt)
        A2[mt] = *(const bf8v*)(hb + ((mt*4 + ks2)*64 + lane)*8);
      #pragma unroll
      for (int nt = 0; nt < 3; ++nt) {
        int ntg = wave*3 + nt;
        int ksg = ch*4 + ks2;
        bf8v B2 = *(const bf8v*)(b2f + ((ntg*24 + ksg)*64 + lane)*8);
        #pragma unroll
        for (int mt = 0; mt < 4; ++mt)
          acc2[mt][nt] = __builtin_amdgcn_mfma_f32_16x16x32_bf16(A2[mt], B2, acc2[mt][nt], 0, 0, 0);
      }
    }
  }

  // ---- epilogue: gamma*(acc+b2), f4v store channels-first
  #pragma unroll
  for (int nt = 0; nt < 3; ++nt) {
    int c = (wave*3 + nt)*16 + ln15;
    float gm = gamma[c], bb = b2[c];
    size_t cbase = ((size_t)(b*CCH + c))*NPOS + (size_t)(y0 + lq)*32 + x0;
    #pragma unroll
    for (int mt = 0; mt < 4; ++mt) {
      f4v o;
      o[0] = gm*(acc2[mt][nt][0] + bb);
      o[1] = gm*(acc2[mt][nt][1] + bb);
      o[2] = gm*(acc2[mt][nt][2] + bb);
      o[3] = gm*(acc2[mt][nt][3] + bb);
      *(f4v*)(out + cbase + (size_t)(z0 + mt)*1024) = o;
    }
  }
}

// ---------------------------------------------------------------------------
extern "C" void kernel_launch(void* const* d_in, const int* in_sizes, int n_in,
                              void* d_out, int out_size, void* d_ws, size_t ws_size,
                              hipStream_t stream) {
  const float* x     = (const float*)d_in[0];
  const int*   mask  = (const int*)  d_in[1];
  const float* dw_w  = (const float*)d_in[2];
  const float* dw_b  = (const float*)d_in[3];
  const float* ln_w  = (const float*)d_in[4];
  const float* ln_b  = (const float*)d_in[5];
  const float* w1    = (const float*)d_in[6];
  const float* b1    = (const float*)d_in[7];
  const float* w2    = (const float*)d_in[8];
  const float* b2    = (const float*)d_in[9];
  const float* gamma = (const float*)d_in[10];
  float* out = (float*)d_out;
  char* ws = (char*)d_ws;

  unsigned short* yc  = (unsigned short*)(ws + WS_Y);
  unsigned short* b1f = (unsigned short*)(ws + WS_B1F);
  unsigned short* b2f = (unsigned short*)(ws + WS_B2F);

  conv_dw_kernel<<<3072, 256, 0, stream>>>(x, dw_w, dw_b, yc);
  prep_w_kernel<<<144, 256, 0, stream>>>(w1, w2, b1f, b2f);
  mlp_kernel<<<1024, 256, 0, stream>>>(yc, b1f, b2f, b1, b2, gamma, ln_w, ln_b, mask, out);
}

// Round 5
// 299.347 us; speedup vs baseline: 1.2959x; 1.2959x over previous
//
#include <hip/hip_runtime.h>
#include <hip/hip_bf16.h>

typedef __attribute__((ext_vector_type(4))) float f4v;
typedef __attribute__((ext_vector_type(8))) short bf8v;

// ---- problem constants ----
#define NPOS 32768            // 32*32*32
#define CCH  192
#define HID  768

// ---- workspace layout (bytes) ----
#define WS_Y    ((size_t)0)           // 2*512*192*64*2 = 25,165,824  conv out bf16, cell layout
#define WS_B1F  ((size_t)25165824)    // 294,912  w1 bf16 B-frag swizzled
#define WS_B2F  ((size_t)25460736)    // 294,912  w2 bf16 B-frag swizzled
// total: 25,755,648 bytes

__device__ inline unsigned short f2bf(float f){
  unsigned int u = __float_as_uint(f);
  u += 0x7FFFu + ((u >> 16) & 1u);      // RNE
  return (unsigned short)(u >> 16);
}
__device__ inline float bf2f(unsigned short s){
  return __uint_as_float(((unsigned int)s) << 16);
}
__device__ inline float gelu_f(float x){
  float u = 0.7978845608028654f * x * fmaf(0.044715f, x*x, 1.0f);
  float e = __expf(2.0f*u);
  float th = __fdividef(e - 1.0f, e + 1.0f);
  return 0.5f*x*(1.0f + th);
}

// ---------------------------------------------------------------------------
// Kernel 1: depthwise 7x7x7 conv + bias. Block = (b, c, 16x16 xy quadrant,
// 16-z half). Input column staged to LDS once; per-channel weights ALSO staged
// to LDS (343 floats) so the s-loop reads them via same-address broadcast
// ds_read instead of 343 serial global loads (round-4 stall suspect).
// Thread = 4dx x 4dy x 1z. Output: bf16 cell-blocked layout
// yc[((b*512+cell)*192+c)*64 + tok], tok = (z&3)*16+(y&3)*4+(x&3).
// ---------------------------------------------------------------------------
__global__ __launch_bounds__(256) void conv_dw_kernel(
    const float* __restrict__ x, const float* __restrict__ dw_w,
    const float* __restrict__ dw_b, unsigned short* __restrict__ yc)
{
  __shared__ float ring[22*528];       // 46,464 B
  __shared__ float wlds[343];          // 1,372 B -> total 47,836 (3 blocks/CU)

  int bid = blockIdx.x;                // 3072 = 192c * 16(r)
  int c = bid % 192;
  int r = bid / 192;                   // 0..15
  int xq = r & 1, yq = (r >> 1) & 1, zh = (r >> 2) & 1, b = r >> 3;
  int tx0 = xq*16, ty0 = yq*16, zb = zh*16;

  int tid = threadIdx.x;
  const float* xsrc = x + ((size_t)(b*CCH + c))*NPOS;

  // ---- stage weights (uniform per block) + input column
  for (int i = tid; i < 343; i += 256) wlds[i] = dw_w[c*343 + i];
  for (int idx = tid; idx < 2904; idx += 256) {   // 22 sl x 22 rows x 6 f4
    int sl = idx / 132;
    int rem = idx - sl*132;
    int rr = rem / 6, ci = rem - rr*6;
    int zi = zb - 3 + sl, gy = ty0 - 3 + rr, gx = tx0 - 4 + 4*ci;
    f4v v = {0.f, 0.f, 0.f, 0.f};
    if ((unsigned)zi < 32u && (unsigned)gy < 32u && (unsigned)gx <= 28u)
      v = *(const f4v*)(xsrc + (size_t)zi*1024 + gy*32 + gx);
    *(f4v*)(ring + sl*528 + rr*24 + ci*4) = v;
  }
  __syncthreads();

  int p = tid & 15, zl = tid >> 4;     // 16 patches, 16 z-planes
  int px = p & 3, py = p >> 2;
  int y0 = py*4, px4 = px*4;
  const float* base = ring + zl*528 + y0*24 + px4;

  float acc[16];
  #pragma unroll
  for (int i = 0; i < 16; ++i) acc[i] = 0.f;

  #pragma unroll 1                     // keep body in I-cache
  for (int s = 0; s < 7; ++s) {
    float wl[49];
    #pragma unroll
    for (int i = 0; i < 49; ++i) wl[i] = wlds[s*49 + i];   // LDS broadcast
    const float* sb = base + s*528;
    f4v n0 = *(const f4v*)(sb);
    f4v n1 = *(const f4v*)(sb + 4);
    f4v n2 = *(const f4v*)(sb + 8);
    #pragma unroll
    for (int rr = 0; rr < 10; ++rr) {
      f4v r0 = n0, r1 = n1, r2 = n2;
      if (rr < 9) {                    // preload next row during FMAs
        n0 = *(const f4v*)(sb + (rr+1)*24);
        n1 = *(const f4v*)(sb + (rr+1)*24 + 4);
        n2 = *(const f4v*)(sb + (rr+1)*24 + 8);
      }
      float row[12];
      row[0]=r0[0]; row[1]=r0[1]; row[2]=r0[2]; row[3]=r0[3];
      row[4]=r1[0]; row[5]=r1[1]; row[6]=r1[2]; row[7]=r1[3];
      row[8]=r2[0]; row[9]=r2[1]; row[10]=r2[2]; row[11]=r2[3];
      #pragma unroll
      for (int dy = 0; dy < 4; ++dy) {
        int ky = rr - dy;
        if (ky < 0 || ky > 6) continue;          // compile-time pruned
        #pragma unroll
        for (int kx = 0; kx < 7; ++kx) {
          float w = wl[ky*7 + kx];
          #pragma unroll
          for (int dx = 0; dx < 4; ++dx)
            acc[dy*4 + dx] = fmaf(w, row[dx + kx + 1], acc[dy*4 + dx]);
        }
      }
    }
  }

  // ---- store bf16 to cell-blocked layout
  float bias = dw_b[c];
  int z = zb + zl;
  int cz = z >> 2, cx = (tx0 >> 2) + px, cy = (ty0 >> 2) + py;
  int cell = cz*64 + cy*8 + cx;
  unsigned short* ybase = yc + (((size_t)(b*512 + cell))*192 + c)*64;
  int tokz = (z & 3)*16;
  #pragma unroll
  for (int dy = 0; dy < 4; ++dy) {
    ushort4 o;
    o.x = f2bf(acc[dy*4+0] + bias);
    o.y = f2bf(acc[dy*4+1] + bias);
    o.z = f2bf(acc[dy*4+2] + bias);
    o.w = f2bf(acc[dy*4+3] + bias);
    *(ushort4*)(ybase + tokz + dy*4) = o;
  }
}

// ---------------------------------------------------------------------------
// Kernel 2: weight prep. w1/w2 -> bf16 MFMA-B-fragment order.
// B-frag (16x16x32): element (k,n) -> lane=((k%32)/8)*16+(n%16), byte j=k%8.
// ---------------------------------------------------------------------------
__global__ __launch_bounds__(256) void prep_w_kernel(
    const float* __restrict__ w1, const float* __restrict__ w2,
    unsigned short* __restrict__ b1f, unsigned short* __restrict__ b2f)
{
  int gid = blockIdx.x*256 + threadIdx.x;
  if (gid < 18432) {
    int fi = gid;                         // w1 (C=192 x HID=768)
    int lane = fi & 63, fr = fi >> 6;
    int nt = fr / 6, ks = fr - nt*6;
    int n  = nt*16 + (lane & 15);
    int kb = ks*32 + (lane >> 4)*8;
    #pragma unroll
    for (int j = 0; j < 8; ++j) b1f[fi*8 + j] = f2bf(w1[(kb+j)*HID + n]);
  } else if (gid < 36864) {
    int fi = gid - 18432;                 // w2 (HID=768 x C=192)
    int lane = fi & 63, fr = fi >> 6;
    int nt = fr / 24, ks = fr - nt*24;
    int n  = nt*16 + (lane & 15);
    int kb = ks*32 + (lane >> 4)*8;
    #pragma unroll
    for (int j = 0; j < 8; ++j) b2f[fi*8 + j] = f2bf(w2[(kb+j)*CCH + n]);
  }
}

// ---------------------------------------------------------------------------
// Kernel 3: fused LN + MLP per active cell.
// Key change vs round 4: A-fragments live in LDS (aFrag), built once with
// coalesced LDS traffic; B1/B2 fragments are BATCH-loaded into explicit
// register arrays (12 outstanding loads each -> one latency drain per batch
// instead of 24 serial load->wait->use chains). LDS: ymat unioned with hbuf.
// ---------------------------------------------------------------------------
__global__ __launch_bounds__(256) void mlp_kernel(
    const unsigned short* __restrict__ yc, const unsigned short* __restrict__ b1f,
    const unsigned short* __restrict__ b2f, const float* __restrict__ b1,
    const float* __restrict__ b2, const float* __restrict__ gamma,
    const float* __restrict__ ln_w, const float* __restrict__ ln_b,
    const int* __restrict__ mask, float* __restrict__ out)
{
  int bid = blockIdx.x;
  int b = bid >> 9, cell = bid & 511;
  int cz = cell >> 6, cy = (cell >> 3) & 7, cx = cell & 7;
  int z0 = cz*4, y0 = cy*4, x0 = cx*4;
  int tid = threadIdx.x, wave = tid >> 6, lane = tid & 63;
  int lq = lane >> 4, ln15 = lane & 15;

  if (mask[bid] == 0) {
    f4v z4 = {0.f, 0.f, 0.f, 0.f};
    #pragma unroll
    for (int pp = 0; pp < 12; ++pp) {
      int i4 = tid + 256*pp;              // 0..3071
      int c = i4 >> 4, rem = i4 & 15;
      int dz = rem >> 2, dy = rem & 3;
      *(f4v*)(out + ((size_t)(b*CCH + c))*NPOS
                  + (size_t)(z0+dz)*1024 + (y0+dy)*32 + x0) = z4;
    }
    return;
  }

  // ---- LDS: ymat (phase 1) unioned with hbuf (phase 2); aFrag persistent
  __shared__ __align__(16) char uni[26112];       // max(192*68*2, 8192*2)
  unsigned short* ymat = (unsigned short*)uni;    // stride 68
  unsigned short* hbuf = (unsigned short*)uni;    // 8192 ushorts, A2-frag order
  __shared__ unsigned short aFrag[12288];         // 24 KB, A1-frag order
  __shared__ float sred[2][4][64];
  __shared__ float murs[2][64];
  // total LDS = 26112+24576+2048+512 = 53248 B -> 3 blocks/CU

  const unsigned short* ysrc = yc + (size_t)bid*12288;

  // ---- stage yc -> ymat (coalesced ushort4)
  #pragma unroll
  for (int k = 0; k < 12; ++k) {
    int idx = tid + 256*k;                  // 0..3071
    int c = idx >> 4, t4 = idx & 15;
    *(ushort4*)(ymat + c*68 + t4*4) = *(const ushort4*)(ysrc + c*64 + t4*4);
  }
  __syncthreads();

  // ---- LN stats: thread (tok = tid&63, part = tid>>6) sums 48 channels
  {
    int tok = tid & 63, part = tid >> 6;
    float S = 0.f, Q = 0.f;
    #pragma unroll
    for (int j = 0; j < 48; ++j) {
      float v = bf2f(ymat[(part*48 + j)*68 + tok]);
      S += v; Q = fmaf(v, v, Q);
    }
    sred[0][part][tok] = S; sred[1][part][tok] = Q;
  }
  __syncthreads();
  if (tid < 64) {
    float S = sred[0][0][tid] + sred[0][1][tid] + sred[0][2][tid] + sred[0][3][tid];
    float Q = sred[1][0][tid] + sred[1][1][tid] + sred[1][2][tid] + sred[1][3][tid];
    float m = S*(1.f/192.f);
    float var = Q*(1.f/192.f) - m*m;
    murs[0][tid] = m;
    murs[1][tid] = rsqrtf(var + 1e-6f);
  }
  __syncthreads();

  // ---- build A-fragments into aFrag (6 frags/thread, b128 coalesced writes)
  #pragma unroll
  for (int k = 0; k < 6; ++k) {
    int fi = tid + 256*k;                   // 0..1535
    int lane2 = fi & 63, rest = fi >> 6;    // rest = wave + 4k (0..23)
    int mt = rest / 6, ks = rest - mt*6;
    int tok = mt*16 + (lane2 & 15);
    int cc0 = ks*32 + (lane2 >> 4)*8;
    float m = murs[0][tok], rs = murs[1][tok];
    union { bf8v v; unsigned short u[8]; } pk;
    #pragma unroll
    for (int j = 0; j < 8; ++j) {
      int cc = cc0 + j;
      float v = (bf2f(ymat[cc*68 + tok]) - m)*rs*ln_w[cc] + ln_b[cc];
      pk.u[j] = f2bf(v);
    }
    *(bf8v*)(aFrag + fi*8) = pk.v;
  }
  __syncthreads();                          // aFrag ready; ymat dead (hbuf reuse ok)

  f4v acc2[4][3];
  #pragma unroll
  for (int mt = 0; mt < 4; ++mt)
    #pragma unroll
    for (int nt = 0; nt < 3; ++nt)
      acc2[mt][nt] = (f4v){0.f, 0.f, 0.f, 0.f};

  #pragma unroll 1                          // keep body in I-cache
  for (int ch = 0; ch < 6; ++ch) {
    // ---- batched B1 prefetch: 12 outstanding global_load_dwordx4
    bf8v B1r[12];
    #pragma unroll
    for (int jj = 0; jj < 2; ++jj)
      #pragma unroll
      for (int ks = 0; ks < 6; ++ks) {
        int nt = ch*8 + wave*2 + jj;
        B1r[jj*6 + ks] = *(const bf8v*)(b1f + ((nt*6 + ks)*64 + lane)*8);
      }
    // ---- GEMM1: A from LDS, B from regs
    f4v a1[2][4];
    #pragma unroll
    for (int jj = 0; jj < 2; ++jj)
      #pragma unroll
      for (int mt = 0; mt < 4; ++mt) a1[jj][mt] = (f4v){0.f,0.f,0.f,0.f};
    #pragma unroll
    for (int ks = 0; ks < 6; ++ks) {
      bf8v Af[4];
      #pragma unroll
      for (int mt = 0; mt < 4; ++mt)
        Af[mt] = *(const bf8v*)(aFrag + ((mt*6 + ks)*64 + lane)*8);
      #pragma unroll
      for (int jj = 0; jj < 2; ++jj)
        #pragma unroll
        for (int mt = 0; mt < 4; ++mt)
          a1[jj][mt] = __builtin_amdgcn_mfma_f32_16x16x32_bf16(Af[mt], B1r[jj*6+ks], a1[jj][mt], 0, 0, 0);
    }
    // ---- batched B2 prefetch (latency overlaps gelu + barrier)
    bf8v B2r[12];
    #pragma unroll
    for (int ks2 = 0; ks2 < 4; ++ks2)
      #pragma unroll
      for (int nt = 0; nt < 3; ++nt) {
        int ntg = wave*3 + nt, ksg = ch*4 + ks2;
        B2r[ks2*3 + nt] = *(const bf8v*)(b2f + ((ntg*24 + ksg)*64 + lane)*8);
      }
    // ---- bias + gelu -> hbuf (A2-frag order)
    #pragma unroll
    for (int jj = 0; jj < 2; ++jj) {
      float b1v = b1[(ch*8 + wave*2 + jj)*16 + ln15];
      int lane_hi = jj*2 + (ln15 >> 3);
      #pragma unroll
      for (int mt = 0; mt < 4; ++mt)
        #pragma unroll
        for (int rr = 0; rr < 4; ++rr) {
          float g = gelu_f(a1[jj][mt][rr] + b1v);
          int elem = ((mt*4 + wave)*64 + lane_hi*16 + (lq*4 + rr))*8 + (lane & 7);
          hbuf[elem] = f2bf(g);
        }
    }
    __syncthreads();
    // ---- GEMM2 partial: acc2 += h_chunk @ w2[ch*128.., :]
    #pragma unroll
    for (int ks2 = 0; ks2 < 4; ++ks2) {
      bf8v A2[4];
      #pragma unroll
      for (int mt = 0; mt < 4; ++mt)
        A2[mt] = *(const bf8v*)(hbuf + ((mt*4 + ks2)*64 + lane)*8);
      #pragma unroll
      for (int nt = 0; nt < 3; ++nt)
        #pragma unroll
        for (int mt = 0; mt < 4; ++mt)
          acc2[mt][nt] = __builtin_amdgcn_mfma_f32_16x16x32_bf16(A2[mt], B2r[ks2*3+nt], acc2[mt][nt], 0, 0, 0);
    }
    __syncthreads();                        // hbuf reused next ch
  }

  // ---- epilogue: gamma*(acc+b2), f4v store channels-first
  #pragma unroll
  for (int nt = 0; nt < 3; ++nt) {
    int c = (wave*3 + nt)*16 + ln15;
    float gm = gamma[c], bb = b2[c];
    size_t cbase = ((size_t)(b*CCH + c))*NPOS + (size_t)(y0 + lq)*32 + x0;
    #pragma unroll
    for (int mt = 0; mt < 4; ++mt) {
      f4v o;
      o[0] = gm*(acc2[mt][nt][0] + bb);
      o[1] = gm*(acc2[mt][nt][1] + bb);
      o[2] = gm*(acc2[mt][nt][2] + bb);
      o[3] = gm*(acc2[mt][nt][3] + bb);
      *(f4v*)(out + cbase + (size_t)(z0 + mt)*1024) = o;
    }
  }
}

// ---------------------------------------------------------------------------
extern "C" void kernel_launch(void* const* d_in, const int* in_sizes, int n_in,
                              void* d_out, int out_size, void* d_ws, size_t ws_size,
                              hipStream_t stream) {
  const float* x     = (const float*)d_in[0];
  const int*   mask  = (const int*)  d_in[1];
  const float* dw_w  = (const float*)d_in[2];
  const float* dw_b  = (const float*)d_in[3];
  const float* ln_w  = (const float*)d_in[4];
  const float* ln_b  = (const float*)d_in[5];
  const float* w1    = (const float*)d_in[6];
  const float* b1    = (const float*)d_in[7];
  const float* w2    = (const float*)d_in[8];
  const float* b2    = (const float*)d_in[9];
  const float* gamma = (const float*)d_in[10];
  float* out = (float*)d_out;
  char* ws = (char*)d_ws;

  unsigned short* yc  = (unsigned short*)(ws + WS_Y);
  unsigned short* b1f = (unsigned short*)(ws + WS_B1F);
  unsigned short* b2f = (unsigned short*)(ws + WS_B2F);

  conv_dw_kernel<<<3072, 256, 0, stream>>>(x, dw_w, dw_b, yc);
  prep_w_kernel<<<144, 256, 0, stream>>>(w1, w2, b1f, b2f);
  mlp_kernel<<<1024, 256, 0, stream>>>(yc, b1f, b2f, b1, b2, gamma, ln_w, ln_b, mask, out);
}

// Round 6
// 296.626 us; speedup vs baseline: 1.3078x; 1.0092x over previous
//
#include <hip/hip_runtime.h>
#include <hip/hip_bf16.h>

typedef __attribute__((ext_vector_type(2))) float f2v;
typedef __attribute__((ext_vector_type(4))) float f4v;
typedef __attribute__((ext_vector_type(8))) short bf8v;

// ---- problem constants ----
#define NPOS 32768            // 32*32*32
#define CCH  192
#define HID  768

// ---- workspace layout (bytes) ----
#define WS_Y    ((size_t)0)           // 2*512*192*64*2 = 25,165,824  conv out bf16, cell layout
#define WS_B1F  ((size_t)25165824)    // 294,912  w1 bf16 B-frag swizzled
#define WS_B2F  ((size_t)25460736)    // 294,912  w2 bf16 B-frag swizzled
// total: 25,755,648 bytes

__device__ inline unsigned short f2bf(float f){
  unsigned int u = __float_as_uint(f);
  u += 0x7FFFu + ((u >> 16) & 1u);      // RNE
  return (unsigned short)(u >> 16);
}
__device__ inline float bf2f(unsigned short s){
  return __uint_as_float(((unsigned int)s) << 16);
}
__device__ inline float gelu_f(float x){
  float u = 0.7978845608028654f * x * fmaf(0.044715f, x*x, 1.0f);
  float e = __expf(2.0f*u);
  float th = __fdividef(e - 1.0f, e + 1.0f);
  return 0.5f*x*(1.0f + th);
}

// ---------------------------------------------------------------------------
// Kernel 1: depthwise 7x7x7 conv + bias, PACKED fp32 (v_pk_fma_f32 target).
// Block = (b, c, 16x16 xy quadrant, 16-z half). Input column + weights staged
// to LDS once (one barrier). Thread = 4dx x 4dy x 1z, accumulators as f2v
// pairs; x-operand pairs p[k]={row[k],row[k+1]} built from conflict-free
// ds_read_b128 quads; weight splat {w,w} hoisted per (s,ky,kx).
// Output: bf16 cell-blocked yc[((b*512+cell)*192+c)*64 + tok].
// ---------------------------------------------------------------------------
__global__ __launch_bounds__(256) void conv_dw_kernel(
    const float* __restrict__ x, const float* __restrict__ dw_w,
    const float* __restrict__ dw_b, unsigned short* __restrict__ yc)
{
  __shared__ float ring[22*528];       // 46,464 B
  __shared__ float wlds[343];          // 1,372 B

  int bid = blockIdx.x;                // 3072 = 192c * 16(r)
  int c = bid % 192;
  int r = bid / 192;                   // 0..15
  int xq = r & 1, yq = (r >> 1) & 1, zh = (r >> 2) & 1, b = r >> 3;
  int tx0 = xq*16, ty0 = yq*16, zb = zh*16;

  int tid = threadIdx.x;
  const float* xsrc = x + ((size_t)(b*CCH + c))*NPOS;

  // ---- stage weights (uniform per block) + input column
  for (int i = tid; i < 343; i += 256) wlds[i] = dw_w[c*343 + i];
  for (int idx = tid; idx < 2904; idx += 256) {   // 22 sl x 22 rows x 6 f4
    int sl = idx / 132;
    int rem = idx - sl*132;
    int rr = rem / 6, ci = rem - rr*6;
    int zi = zb - 3 + sl, gy = ty0 - 3 + rr, gx = tx0 - 4 + 4*ci;
    f4v v = {0.f, 0.f, 0.f, 0.f};
    if ((unsigned)zi < 32u && (unsigned)gy < 32u && (unsigned)gx <= 28u)
      v = *(const f4v*)(xsrc + (size_t)zi*1024 + gy*32 + gx);
    *(f4v*)(ring + sl*528 + rr*24 + ci*4) = v;
  }
  __syncthreads();

  int p = tid & 15, zl = tid >> 4;     // 16 patches, 16 z-planes
  int px = p & 3, py = p >> 2;
  int y0 = py*4, px4 = px*4;
  const float* base = ring + zl*528 + y0*24 + px4;

  f2v acc[8];                          // acc[dy*2+h] = outputs dx={2h,2h+1}
  #pragma unroll
  for (int i = 0; i < 8; ++i) acc[i] = (f2v){0.f, 0.f};

  #pragma unroll 1                     // keep body in I-cache
  for (int s = 0; s < 7; ++s) {
    float wl[49];
    #pragma unroll
    for (int i = 0; i < 49; ++i) wl[i] = wlds[s*49 + i];   // LDS broadcast
    const float* sb = base + s*528;
    f4v n0 = *(const f4v*)(sb);
    f4v n1 = *(const f4v*)(sb + 4);
    f4v n2 = *(const f4v*)(sb + 8);
    #pragma unroll
    for (int rr = 0; rr < 10; ++rr) {
      f4v r0 = n0, r1 = n1, r2 = n2;
      if (rr < 9) {                    // preload next row during FMAs
        n0 = *(const f4v*)(sb + (rr+1)*24);
        n1 = *(const f4v*)(sb + (rr+1)*24 + 4);
        n2 = *(const f4v*)(sb + (rr+1)*24 + 8);
      }
      // sliding pairs p[k] = {row[k], row[k+1]}, k = 1..9
      f2v pr[10];
      pr[1] = (f2v){r0[1], r0[2]};
      pr[2] = (f2v){r0[2], r0[3]};
      pr[3] = (f2v){r0[3], r1[0]};
      pr[4] = (f2v){r1[0], r1[1]};
      pr[5] = (f2v){r1[1], r1[2]};
      pr[6] = (f2v){r1[2], r1[3]};
      pr[7] = (f2v){r1[3], r2[0]};
      pr[8] = (f2v){r2[0], r2[1]};
      pr[9] = (f2v){r2[1], r2[2]};
      #pragma unroll
      for (int dy = 0; dy < 4; ++dy) {
        int ky = rr - dy;
        if (ky < 0 || ky > 6) continue;          // compile-time pruned
        #pragma unroll
        for (int kx = 0; kx < 7; ++kx) {
          float w = wl[ky*7 + kx];
          f2v wv = {w, w};
          acc[dy*2+0] = __builtin_elementwise_fma(wv, pr[kx+1], acc[dy*2+0]);
          acc[dy*2+1] = __builtin_elementwise_fma(wv, pr[kx+3], acc[dy*2+1]);
        }
      }
    }
  }

  // ---- store bf16 to cell-blocked layout
  float bias = dw_b[c];
  int z = zb + zl;
  int cz = z >> 2, cx = (tx0 >> 2) + px, cy = (ty0 >> 2) + py;
  int cell = cz*64 + cy*8 + cx;
  unsigned short* ybase = yc + (((size_t)(b*512 + cell))*192 + c)*64;
  int tokz = (z & 3)*16;
  #pragma unroll
  for (int dy = 0; dy < 4; ++dy) {
    ushort4 o;
    o.x = f2bf(acc[dy*2+0][0] + bias);
    o.y = f2bf(acc[dy*2+0][1] + bias);
    o.z = f2bf(acc[dy*2+1][0] + bias);
    o.w = f2bf(acc[dy*2+1][1] + bias);
    *(ushort4*)(ybase + tokz + dy*4) = o;
  }
}

// ---------------------------------------------------------------------------
// Kernel 2: weight prep. w1/w2 -> bf16 MFMA-B-fragment order.
// B-frag (16x16x32): element (k,n) -> lane=((k%32)/8)*16+(n%16), byte j=k%8.
// ---------------------------------------------------------------------------
__global__ __launch_bounds__(256) void prep_w_kernel(
    const float* __restrict__ w1, const float* __restrict__ w2,
    unsigned short* __restrict__ b1f, unsigned short* __restrict__ b2f)
{
  int gid = blockIdx.x*256 + threadIdx.x;
  if (gid < 18432) {
    int fi = gid;                         // w1 (C=192 x HID=768)
    int lane = fi & 63, fr = fi >> 6;
    int nt = fr / 6, ks = fr - nt*6;
    int n  = nt*16 + (lane & 15);
    int kb = ks*32 + (lane >> 4)*8;
    #pragma unroll
    for (int j = 0; j < 8; ++j) b1f[fi*8 + j] = f2bf(w1[(kb+j)*HID + n]);
  } else if (gid < 36864) {
    int fi = gid - 18432;                 // w2 (HID=768 x C=192)
    int lane = fi & 63, fr = fi >> 6;
    int nt = fr / 24, ks = fr - nt*24;
    int n  = nt*16 + (lane & 15);
    int kb = ks*32 + (lane >> 4)*8;
    #pragma unroll
    for (int j = 0; j < 8; ++j) b2f[fi*8 + j] = f2bf(w2[(kb+j)*CCH + n]);
  }
}

// ---------------------------------------------------------------------------
// Kernel 3: fused LN + MLP per active cell, software-pipelined B loads:
// B2r(ch) loaded at loop top (drain covered by GEMM1); B1r(ch+1) prefetched
// right after GEMM1's last use (drain covered by gelu+barrier+GEMM2).
// A-fragments in LDS; ln_w/ln_b as batched f4v loads.
// ---------------------------------------------------------------------------
__global__ __launch_bounds__(256) void mlp_kernel(
    const unsigned short* __restrict__ yc, const unsigned short* __restrict__ b1f,
    const unsigned short* __restrict__ b2f, const float* __restrict__ b1,
    const float* __restrict__ b2, const float* __restrict__ gamma,
    const float* __restrict__ ln_w, const float* __restrict__ ln_b,
    const int* __restrict__ mask, float* __restrict__ out)
{
  int bid = blockIdx.x;
  int b = bid >> 9, cell = bid & 511;
  int cz = cell >> 6, cy = (cell >> 3) & 7, cx = cell & 7;
  int z0 = cz*4, y0 = cy*4, x0 = cx*4;
  int tid = threadIdx.x, wave = tid >> 6, lane = tid & 63;
  int lq = lane >> 4, ln15 = lane & 15;

  if (mask[bid] == 0) {
    f4v z4 = {0.f, 0.f, 0.f, 0.f};
    #pragma unroll
    for (int pp = 0; pp < 12; ++pp) {
      int i4 = tid + 256*pp;              // 0..3071
      int c = i4 >> 4, rem = i4 & 15;
      int dz = rem >> 2, dy = rem & 3;
      *(f4v*)(out + ((size_t)(b*CCH + c))*NPOS
                  + (size_t)(z0+dz)*1024 + (y0+dy)*32 + x0) = z4;
    }
    return;
  }

  // ---- LDS: ymat (phase 1) unioned with hbuf (phase 2); aFrag persistent
  __shared__ __align__(16) char uni[26112];       // max(192*68*2, 8192*2)
  unsigned short* ymat = (unsigned short*)uni;    // stride 68
  unsigned short* hbuf = (unsigned short*)uni;    // 8192 ushorts, A2-frag order
  __shared__ unsigned short aFrag[12288];         // 24 KB, A1-frag order
  __shared__ float sred[2][4][64];
  __shared__ float murs[2][64];
  // total 53,248 B -> 3 blocks/CU

  const unsigned short* ysrc = yc + (size_t)bid*12288;

  // ---- stage yc -> ymat (coalesced ushort4)
  #pragma unroll
  for (int k = 0; k < 12; ++k) {
    int idx = tid + 256*k;                  // 0..3071
    int c = idx >> 4, t4 = idx & 15;
    *(ushort4*)(ymat + c*68 + t4*4) = *(const ushort4*)(ysrc + c*64 + t4*4);
  }
  __syncthreads();

  // ---- LN stats: thread (tok = tid&63, part = tid>>6) sums 48 channels
  {
    int tok = tid & 63, part = tid >> 6;
    float S = 0.f, Q = 0.f;
    #pragma unroll
    for (int j = 0; j < 48; ++j) {
      float v = bf2f(ymat[(part*48 + j)*68 + tok]);
      S += v; Q = fmaf(v, v, Q);
    }
    sred[0][part][tok] = S; sred[1][part][tok] = Q;
  }
  __syncthreads();
  if (tid < 64) {
    float S = sred[0][0][tid] + sred[0][1][tid] + sred[0][2][tid] + sred[0][3][tid];
    float Q = sred[1][0][tid] + sred[1][1][tid] + sred[1][2][tid] + sred[1][3][tid];
    float m = S*(1.f/192.f);
    float var = Q*(1.f/192.f) - m*m;
    murs[0][tid] = m;
    murs[1][tid] = rsqrtf(var + 1e-6f);
  }
  __syncthreads();

  // ---- build A-fragments into aFrag (6 frags/thread, b128 coalesced writes)
  #pragma unroll
  for (int k = 0; k < 6; ++k) {
    int fi = tid + 256*k;                   // 0..1535
    int lane2 = fi & 63, rest = fi >> 6;
    int mt = rest / 6, ks = rest - mt*6;
    int tok = mt*16 + (lane2 & 15);
    int cc0 = ks*32 + (lane2 >> 4)*8;
    float m = murs[0][tok], rs = murs[1][tok];
    f4v lw0 = *(const f4v*)(ln_w + cc0), lw1 = *(const f4v*)(ln_w + cc0 + 4);
    f4v lb0 = *(const f4v*)(ln_b + cc0), lb1 = *(const f4v*)(ln_b + cc0 + 4);
    union { bf8v v; unsigned short u[8]; } pk;
    #pragma unroll
    for (int j = 0; j < 4; ++j) {
      float v0 = (bf2f(ymat[(cc0+j)*68 + tok])   - m)*rs*lw0[j] + lb0[j];
      float v1 = (bf2f(ymat[(cc0+4+j)*68 + tok]) - m)*rs*lw1[j] + lb1[j];
      pk.u[j] = f2bf(v0); pk.u[4+j] = f2bf(v1);
    }
    *(bf8v*)(aFrag + fi*8) = pk.v;
  }
  __syncthreads();                          // aFrag ready; ymat dead

  f4v acc2[4][3];
  #pragma unroll
  for (int mt = 0; mt < 4; ++mt)
    #pragma unroll
    for (int nt = 0; nt < 3; ++nt)
      acc2[mt][nt] = (f4v){0.f, 0.f, 0.f, 0.f};

  // ---- pipelined B fragment pointers (ushort units)
  const unsigned short* p1base = b1f + wave*2*3072 + lane*8;   // + ch*24576
  const unsigned short* p2base = b2f + wave*3*12288 + lane*8;  // + ch*2048

  bf8v B1r[12];
  #pragma unroll
  for (int i = 0; i < 12; ++i) {            // preload B1 for ch=0
    int jj = i / 6, ks = i - jj*6;
    B1r[i] = *(const bf8v*)(p1base + jj*3072 + ks*512);
  }

  #pragma unroll 1                          // keep body in I-cache
  for (int ch = 0; ch < 6; ++ch) {
    // ---- B2r(ch): 12 outstanding loads, drain covered by GEMM1
    bf8v B2r[12];
    const unsigned short* p2 = p2base + ch*2048;
    #pragma unroll
    for (int i = 0; i < 12; ++i) {
      int ks2 = i >> 2, nt = i & 3; (void)0;  // layout below uses [ks2*3+nt]
    }
    #pragma unroll
    for (int ks2 = 0; ks2 < 4; ++ks2)
      #pragma unroll
      for (int nt = 0; nt < 3; ++nt)
        B2r[ks2*3 + nt] = *(const bf8v*)(p2 + nt*12288 + ks2*512);

    // ---- GEMM1: A from LDS, B1 from regs
    f4v a1[2][4];
    #pragma unroll
    for (int jj = 0; jj < 2; ++jj)
      #pragma unroll
      for (int mt = 0; mt < 4; ++mt) a1[jj][mt] = (f4v){0.f,0.f,0.f,0.f};
    #pragma unroll
    for (int ks = 0; ks < 6; ++ks) {
      bf8v Af[4];
      #pragma unroll
      for (int mt = 0; mt < 4; ++mt)
        Af[mt] = *(const bf8v*)(aFrag + ((mt*6 + ks)*64 + lane)*8);
      #pragma unroll
      for (int jj = 0; jj < 2; ++jj)
        #pragma unroll
        for (int mt = 0; mt < 4; ++mt)
          a1[jj][mt] = __builtin_amdgcn_mfma_f32_16x16x32_bf16(Af[mt], B1r[jj*6+ks], a1[jj][mt], 0, 0, 0);
    }

    // ---- prefetch B1r(ch+1): drain covered by gelu + barrier + GEMM2
    if (ch < 5) {
      const unsigned short* p1 = p1base + (ch+1)*24576;
      #pragma unroll
      for (int i = 0; i < 12; ++i) {
        int jj = i / 6, ks = i - jj*6;
        B1r[i] = *(const bf8v*)(p1 + jj*3072 + ks*512);
      }
    }

    // ---- bias + gelu -> hbuf (A2-frag order)
    #pragma unroll
    for (int jj = 0; jj < 2; ++jj) {
      float b1v = b1[(ch*8 + wave*2 + jj)*16 + ln15];
      int lane_hi = jj*2 + (ln15 >> 3);
      #pragma unroll
      for (int mt = 0; mt < 4; ++mt)
        #pragma unroll
        for (int rr = 0; rr < 4; ++rr) {
          float g = gelu_f(a1[jj][mt][rr] + b1v);
          int elem = ((mt*4 + wave)*64 + lane_hi*16 + (lq*4 + rr))*8 + (lane & 7);
          hbuf[elem] = f2bf(g);
        }
    }
    __syncthreads();
    // ---- GEMM2 partial: acc2 += h_chunk @ w2[ch*128.., :]
    #pragma unroll
    for (int ks2 = 0; ks2 < 4; ++ks2) {
      bf8v A2[4];
      #pragma unroll
      for (int mt = 0; mt < 4; ++mt)
        A2[mt] = *(const bf8v*)(hbuf + ((mt*4 + ks2)*64 + lane)*8);
      #pragma unroll
      for (int nt = 0; nt < 3; ++nt)
        #pragma unroll
        for (int mt = 0; mt < 4; ++mt)
          acc2[mt][nt] = __builtin_amdgcn_mfma_f32_16x16x32_bf16(A2[mt], B2r[ks2*3+nt], acc2[mt][nt], 0, 0, 0);
    }
    __syncthreads();                        // hbuf reused next ch
  }

  // ---- epilogue: gamma*(acc+b2), f4v store channels-first
  #pragma unroll
  for (int nt = 0; nt < 3; ++nt) {
    int c = (wave*3 + nt)*16 + ln15;
    float gm = gamma[c], bb = b2[c];
    size_t cbase = ((size_t)(b*CCH + c))*NPOS + (size_t)(y0 + lq)*32 + x0;
    #pragma unroll
    for (int mt = 0; mt < 4; ++mt) {
      f4v o;
      o[0] = gm*(acc2[mt][nt][0] + bb);
      o[1] = gm*(acc2[mt][nt][1] + bb);
      o[2] = gm*(acc2[mt][nt][2] + bb);
      o[3] = gm*(acc2[mt][nt][3] + bb);
      *(f4v*)(out + cbase + (size_t)(z0 + mt)*1024) = o;
    }
  }
}

// ---------------------------------------------------------------------------
extern "C" void kernel_launch(void* const* d_in, const int* in_sizes, int n_in,
                              void* d_out, int out_size, void* d_ws, size_t ws_size,
                              hipStream_t stream) {
  const float* x     = (const float*)d_in[0];
  const int*   mask  = (const int*)  d_in[1];
  const float* dw_w  = (const float*)d_in[2];
  const float* dw_b  = (const float*)d_in[3];
  const float* ln_w  = (const float*)d_in[4];
  const float* ln_b  = (const float*)d_in[5];
  const float* w1    = (const float*)d_in[6];
  const float* b1    = (const float*)d_in[7];
  const float* w2    = (const float*)d_in[8];
  const float* b2    = (const float*)d_in[9];
  const float* gamma = (const float*)d_in[10];
  float* out = (float*)d_out;
  char* ws = (char*)d_ws;

  unsigned short* yc  = (unsigned short*)(ws + WS_Y);
  unsigned short* b1f = (unsigned short*)(ws + WS_B1F);
  unsigned short* b2f = (unsigned short*)(ws + WS_B2F);

  prep_w_kernel<<<144, 256, 0, stream>>>(w1, w2, b1f, b2f);
  conv_dw_kernel<<<3072, 256, 0, stream>>>(x, dw_w, dw_b, yc);
  mlp_kernel<<<1024, 256, 0, stream>>>(yc, b1f, b2f, b1, b2, gamma, ln_w, ln_b, mask, out);
}